// Round 9
// baseline (4018.449 us; speedup 1.0000x reference)
//
#include <hip/hip_runtime.h>
#include <hip/hip_bf16.h>

#define BB 64
#define SS 128
#define DD 1024
#define HH 16
#define DHH 64
#define FF 3072
#define QS 3072      /* fused qkv row stride */
#define NLAYER 8
#define TT (BB*SS)   /* 8192 tokens */
#define NEGV -1e9f
#define EPSV 1e-5f

typedef __bf16 bf16;
typedef __bf16 bf16x4 __attribute__((ext_vector_type(4)));
typedef __bf16 bf16x8 __attribute__((ext_vector_type(8)));
typedef float f32x4 __attribute__((ext_vector_type(4)));

#define WS_NEEDED 88084480ull  /* 84 MB + flag page (proven available) */
#define FLAG_OFF  88080384ull

// dtype-flexible scalar load: f==1 -> fp32 data, f==0 -> bf16 data
__device__ __forceinline__ float ldf(const void* p, long idx, int f) {
  return f ? ((const float*)p)[idx] : (float)((const bf16*)p)[idx];
}

// diagnostic: report ws_size (in MB) through the output if workspace too small
__global__ __launch_bounds__(256) void diag_kernel(bf16* __restrict__ out, float val) {
  int base = blockIdx.x * 1024 + threadIdx.x * 4;
  for (int j = 0; j < 4; j++) out[base + j] = (bf16)val;
}

// ---------------- dtype detection: scan first 2048 halves of atoms_emb ----------------
__global__ __launch_bounds__(256) void detect_kernel(const unsigned short* __restrict__ p,
                                                     int n, int* __restrict__ flag) {
  __shared__ int sh[4];
  int found = 0;
  for (int i = threadIdx.x; i < n; i += 256) {
    unsigned e = (p[i] >> 7) & 0xFF;
    found |= (e >= 0x7F);
  }
  for (int d = 1; d < 64; d <<= 1) found |= __shfl_xor(found, d);
  if ((threadIdx.x & 63) == 0) sh[threadIdx.x >> 6] = found;
  __syncthreads();
  if (threadIdx.x == 0) *flag = sh[0] | sh[1] | sh[2] | sh[3];
}

// ---------------- weight transpose: W[K][N] (fp32 or bf16) -> WT[N][K] (bf16) ----------------
__global__ __launch_bounds__(256) void transpose_kernel(const void* __restrict__ W,
                                                        bf16* __restrict__ WT, int K, int N,
                                                        const int* __restrict__ dflag) {
  __shared__ bf16 tbuf[32][33];
  const int f = *dflag;
  int n0 = blockIdx.x * 32, k0 = blockIdx.y * 32;
  int tx = threadIdx.x & 31, ty = threadIdx.x >> 5;   // 32 x 8
  for (int i = 0; i < 4; i++)
    tbuf[ty + i*8][tx] = (bf16)ldf(W, (long)(k0 + ty + i*8) * N + n0 + tx, f);
  __syncthreads();
  for (int i = 0; i < 4; i++)
    WT[(long)(n0 + ty + i*8) * K + k0 + tx] = tbuf[tx][ty + i*8];
}

// ---------------- embedding ----------------
__global__ __launch_bounds__(256) void embed_kernel(const int* __restrict__ atoms,
                                                    const int* __restrict__ neigh,
                                                    const void* __restrict__ a_emb,
                                                    const void* __restrict__ n_emb,
                                                    bf16* __restrict__ xb,
                                                    const int* __restrict__ dflag) {
  const int f = *dflag;
  int t = blockIdx.x;
  int a = atoms[t], n = neigh[t];
  int c0 = threadIdx.x * 4;
  bf16x4 o;
  for (int j = 0; j < 4; j++) {
    float va = (a != 0) ? ldf(a_emb, (long)a * DD + c0 + j, f) : 0.0f;
    float vn = (n != 0) ? ldf(n_emb, (long)n * DD + c0 + j, f) : 0.0f;
    o[j] = (bf16)(va + vn);
  }
  *(bf16x4*)(xb + (long)t * DD + c0) = o;
}

// ---------------- GEMM: C[M][N] = A[M][K](lda) @ Bt[N][K]^T + bias ----------------
// EPI: 1 = bf16 out, 2 = + exact GELU.  NBIAS: 1 = bias[N], 3 = three 1024-biases.
// 128x128 tile, BK=64. A staged through ping-pong LDS (single barrier/iter, XOR-swizzled,
// conflict-free). B-fragments loaded DIRECTLY from global (Bt rows are 16B-contiguous
// fragments; weights are L2/LLC-hot) -- halves LDS-pipe traffic, B rides the VMEM pipe.
// Both A-staging and B-frag loads are software-pipelined one iter ahead, so the barrier's
// vmcnt drain lands on ~400-cycle-old loads.
template<int EPI, int NBIAS>
__global__ __launch_bounds__(256) void gemm_bt(const bf16* __restrict__ A,
                                               const bf16* __restrict__ Bt,
                                               const void* __restrict__ bp0,
                                               const void* __restrict__ bp1,
                                               const void* __restrict__ bp2,
                                               bf16* __restrict__ Cout,
                                               int lda, int N, int K,
                                               const int* __restrict__ dflag) {
  __shared__ __align__(16) bf16 Ald[2][2][128][32];   // [pingpong][chunk][row][32k]
  const int f = *dflag;
  const int tid  = threadIdx.x;
  const int l    = tid & 63;
  const int quad = l >> 4, l16 = l & 15;
  const int w    = tid >> 6, wr = w >> 1, wc = w & 1;
  const int m0   = blockIdx.y * 128;
  const int n0   = blockIdx.x * 128;

  // A staging: row r0 / r0+64, 16B chunk c0; swizzled LDS column (bits1-2 of row)
  const int r0 = tid >> 2, c0 = tid & 3;
  const int cs = (c0 ^ ((r0 >> 1) & 3)) * 8;      // store column
  const int cr = (quad ^ ((l16 >> 1) & 3)) * 8;   // read column (same swizzle)
  const bf16* Ap0 = A + (long)(m0 + r0)      * lda + c0*8;
  const bf16* Ap1 = A + (long)(m0 + 64 + r0) * lda + c0*8;
  // B fragment pointers: row n = n0 + wc*64 + j*16 + l16, 16B at k-offset quad*8
  const bf16* Bf[4];
  for (int j = 0; j < 4; j++)
    Bf[j] = Bt + (long)(n0 + wc*64 + j*16 + l16) * K + quad*8;

  f32x4 acc[4][4] = {};

  bf16x8 ra[2][2], rbf[2][4];
  for (int s = 0; s < 2; s++) {
    ra[s][0] = *(const bf16x8*)(Ap0 + s*32);
    ra[s][1] = *(const bf16x8*)(Ap1 + s*32);
    for (int j = 0; j < 4; j++)
      rbf[s][j] = *(const bf16x8*)(Bf[j] + s*32);
  }

  int p = 0;
  for (int kt = 0; kt < K; kt += 64) {
    // store staged A regs -> LDS buffer p
    for (int s = 0; s < 2; s++) {
      *(bf16x8*)&Ald[p][s][r0][cs]      = ra[s][0];
      *(bf16x8*)&Ald[p][s][64 + r0][cs] = ra[s][1];
    }
    __syncthreads();   // single barrier: also separates reads of buf p (2 iters ago)

    // current-iter B frags move to locals; prefetch next-iter A and B
    bf16x8 curB[2][4];
    for (int s = 0; s < 2; s++)
      for (int j = 0; j < 4; j++) curB[s][j] = rbf[s][j];
    if (kt + 64 < K) {
      const int kn = kt + 64;
      for (int s = 0; s < 2; s++) {
        ra[s][0] = *(const bf16x8*)(Ap0 + kn + s*32);
        ra[s][1] = *(const bf16x8*)(Ap1 + kn + s*32);
        for (int j = 0; j < 4; j++)
          rbf[s][j] = *(const bf16x8*)(Bf[j] + kn + s*32);
      }
    }

    for (int s = 0; s < 2; s++) {
      bf16x8 af[4];
      for (int i = 0; i < 4; i++)
        af[i] = *(const bf16x8*)&Ald[p][s][wr*64 + i*16 + l16][cr];
      for (int i = 0; i < 4; i++)
        for (int j = 0; j < 4; j++)
          acc[i][j] = __builtin_amdgcn_mfma_f32_16x16x32_bf16(af[i], curB[s][j], acc[i][j], 0, 0, 0);
    }
    p ^= 1;
  }

  for (int i = 0; i < 4; i++) {
    for (int j = 0; j < 4; j++) {
      int col = n0 + wc*64 + j*16 + l16;
      float bv;
      if (NBIAS == 3) {
        int seg = col >> 10, off = col & 1023;
        const void* bp = (seg == 0) ? bp0 : ((seg == 1) ? bp1 : bp2);
        bv = ldf(bp, off, f);
      } else {
        bv = ldf(bp0, col, f);
      }
      for (int r = 0; r < 4; r++) {
        int row = m0 + wr*64 + i*16 + quad*4 + r;
        float v = acc[i][j][r] + bv;
        if (EPI == 2) v = 0.5f * v * (1.0f + erff(v * 0.70710678118f));
        Cout[(long)row * N + col] = (bf16)v;
      }
    }
  }
}

// ---------------- attention on fused qkv buffer: one block per (b,h) ----------------
__global__ __launch_bounds__(256) void attn_kernel(bf16* __restrict__ qkv,
                                                   const int* __restrict__ dist,
                                                   const void* __restrict__ demb,
                                                   const int* __restrict__ dflag) {
  __shared__ __align__(16) bf16 Vt[DHH][SS + 8];
  __shared__ __align__(16) bf16 Pb[4][32][SS + 8];
  __shared__ float dtab[16];
  const int f = *dflag;
  const int b = blockIdx.x >> 4, h = blockIdx.x & 15;
  const int tid = threadIdx.x;
  const int w = tid >> 6, l = tid & 63, quad = l >> 4, l16 = l & 15;
  if (tid < 13) dtab[tid] = (tid == 0) ? NEGV : ldf(demb, tid * HH + h, f);

  const long rowb = (long)b * SS;
  for (int i = 0; i < 4; i++) {
    int task = tid + i * 256;
    int kk = task >> 3, ng = task & 7;
    bf16x8 vv = *(const bf16x8*)(qkv + (rowb + kk) * QS + 2048 + h*DHH + ng*8);
    for (int u = 0; u < 8; u++) Vt[ng*8 + u][kk] = vv[u];
  }
  __syncthreads();

  const int qbase = w * 32;
  f32x4 acc[2][8] = {};
  for (int ks = 0; ks < 2; ks++) {
    bf16x8 af[2];
    for (int ti = 0; ti < 2; ti++)
      af[ti] = *(const bf16x8*)(qkv + (rowb + qbase + ti*16 + l16) * QS + h*DHH + ks*32 + quad*8);
    for (int tj = 0; tj < 8; tj++) {
      bf16x8 bfr = *(const bf16x8*)(qkv + (rowb + tj*16 + l16) * QS + 1024 + h*DHH + ks*32 + quad*8);
      for (int ti = 0; ti < 2; ti++)
        acc[ti][tj] = __builtin_amdgcn_mfma_f32_16x16x32_bf16(af[ti], bfr, acc[ti][tj], 0, 0, 0);
    }
  }

  const float scale = 0.125f;  // 1/sqrt(64)
  for (int ti = 0; ti < 2; ti++) {
    for (int r = 0; r < 4; r++) {
      int q = qbase + ti*16 + quad*4 + r;
      const int* drow = dist + (rowb + q) * SS;
      float vals[8];
      float mx = -3.0e38f;
      for (int tj = 0; tj < 8; tj++) {
        float sv = acc[ti][tj][r] * scale + dtab[drow[tj*16 + l16]];
        vals[tj] = sv; mx = fmaxf(mx, sv);
      }
      for (int d2 = 1; d2 < 16; d2 <<= 1) mx = fmaxf(mx, __shfl_xor(mx, d2));
      float sm = 0.0f;
      for (int tj = 0; tj < 8; tj++) { vals[tj] = __expf(vals[tj] - mx); sm += vals[tj]; }
      for (int d2 = 1; d2 < 16; d2 <<= 1) sm += __shfl_xor(sm, d2);
      float inv = 1.0f / sm;
      int pr = ti*16 + quad*4 + r;
      for (int tj = 0; tj < 8; tj++)
        Pb[w][pr][tj*16 + l16] = (bf16)(vals[tj] * inv);
    }
  }
  __syncthreads();

  f32x4 acc2[2][4] = {};
  for (int ks = 0; ks < 4; ks++) {
    bf16x8 af[2];
    for (int ti = 0; ti < 2; ti++)
      af[ti] = *(const bf16x8*)&Pb[w][ti*16 + l16][ks*32 + quad*8];
    for (int tj = 0; tj < 4; tj++) {
      bf16x8 bfr = *(const bf16x8*)&Vt[tj*16 + l16][ks*32 + quad*8];
      for (int ti = 0; ti < 2; ti++)
        acc2[ti][tj] = __builtin_amdgcn_mfma_f32_16x16x32_bf16(af[ti], bfr, acc2[ti][tj], 0, 0, 0);
    }
  }
  for (int ti = 0; ti < 2; ti++)
    for (int tj = 0; tj < 4; tj++)
      for (int r = 0; r < 4; r++) {
        int q = qbase + ti*16 + quad*4 + r;
        qkv[(rowb + q) * QS + h*DHH + tj*16 + l16] = (bf16)acc2[ti][tj][r];
      }
}

// ---------------- fused residual add + LayerNorm (post-LN) ----------------
__global__ __launch_bounds__(256) void add_ln_kernel(bf16* __restrict__ x,
                                                     const bf16* __restrict__ tmp,
                                                     const void* __restrict__ g,
                                                     const void* __restrict__ bta,
                                                     const int* __restrict__ dflag) {
  const int f = *dflag;
  int r = blockIdx.x, tid = threadIdx.x;
  int c0 = tid * 4;
  bf16x4 xv = *(const bf16x4*)(x + (long)r*DD + c0);
  bf16x4 tv = *(const bf16x4*)(tmp + (long)r*DD + c0);
  float v[4];
  for (int j = 0; j < 4; j++) v[j] = (float)xv[j] + (float)tv[j];
  float s  = v[0] + v[1] + v[2] + v[3];
  float s2 = v[0]*v[0] + v[1]*v[1] + v[2]*v[2] + v[3]*v[3];
  for (int d2 = 1; d2 < 64; d2 <<= 1) { s += __shfl_xor(s, d2); s2 += __shfl_xor(s2, d2); }
  __shared__ float ws1[4], ws2[4];
  int w = tid >> 6, l = tid & 63;
  if (l == 0) { ws1[w] = s; ws2[w] = s2; }
  __syncthreads();
  s  = ws1[0] + ws1[1] + ws1[2] + ws1[3];
  s2 = ws2[0] + ws2[1] + ws2[2] + ws2[3];
  float mu  = s * (1.0f / DD);
  float var = s2 * (1.0f / DD) - mu * mu;
  float rs  = rsqrtf(var + EPSV);
  bf16x4 o;
  for (int j = 0; j < 4; j++)
    o[j] = (bf16)((v[j] - mu) * rs * ldf(g, c0 + j, f) + ldf(bta, c0 + j, f));
  *(bf16x4*)(x + (long)r*DD + c0) = o;
}

// ---------------- finalize: bf16 scratch -> d_out in detected dtype; NaN tripwire ----------------
__global__ __launch_bounds__(256) void finalize_kernel(const bf16* __restrict__ src,
                                                       void* __restrict__ dst,
                                                       const int* __restrict__ dflag) {
  const int f = *dflag;
  long i = (long)blockIdx.x * 1024 + threadIdx.x * 4;
  for (int j = 0; j < 4; j++) {
    float v = (float)src[i + j];
    if (v != v) v = 777.0f;
    if (f) ((float*)dst)[i + j] = v;
    else   ((bf16*)dst)[i + j] = (bf16)v;
  }
}

extern "C" void kernel_launch(void* const* d_in, const int* in_sizes, int n_in,
                              void* d_out, int out_size, void* d_ws, size_t ws_size,
                              hipStream_t stream) {
  (void)in_sizes; (void)n_in; (void)out_size;
  const int*  atoms     = (const int*)d_in[0];
  const int*  neighbors = (const int*)d_in[1];
  const int*  distances = (const int*)d_in[2];
  const void* atoms_emb = d_in[3];
  const void* neigh_emb = d_in[4];
  const void* dist_emb  = d_in[5];
  const void* wq = d_in[6];
  const void* bq = d_in[7];
  const void* wk = d_in[8];
  const void* bk = d_in[9];
  const void* wv = d_in[10];
  const void* bv = d_in[11];
  const void* wo = d_in[12];
  const void* bo = d_in[13];
  const void* ln1_g = d_in[14];
  const void* ln1_b = d_in[15];
  const void* w1 = d_in[16];
  const void* b1 = d_in[17];
  const void* w2 = d_in[18];
  const void* b2 = d_in[19];
  const void* ln2_g = d_in[20];
  const void* ln2_b = d_in[21];

  if (ws_size < WS_NEEDED) {
    diag_kernel<<<TT, 256, 0, stream>>>((bf16*)d_out, (float)(ws_size >> 20));
    return;
  }

  char* ws = (char*)d_ws;
  bf16* qkv   = (bf16*)(ws);                  // [8192][3072] fused q|k|v; also FFN hbuf
  bf16* tmp2  = (bf16*)(ws + 50331648);       // [8192][1024]
  bf16* wqkvT = (bf16*)(ws + 67108864);       // [3072][1024]
  bf16* woT   = (bf16*)(ws + 73400320);       // [1024][1024]
  bf16* w1T   = (bf16*)(ws + 75497472);       // [3072][1024]
  bf16* w2T   = (bf16*)(ws + 81788928);       // [1024][3072]
  int*  dflag = (int*)(ws + FLAG_OFF);
  bf16* xb    = (bf16*)d_out;                 // bf16 residual stream

  detect_kernel<<<1, 256, 0, stream>>>((const unsigned short*)atoms_emb, 2048, dflag);

  transpose_kernel<<<dim3(32, 32), 256, 0, stream>>>(wq, wqkvT,           1024, 1024, dflag);
  transpose_kernel<<<dim3(32, 32), 256, 0, stream>>>(wk, wqkvT + 1048576, 1024, 1024, dflag);
  transpose_kernel<<<dim3(32, 32), 256, 0, stream>>>(wv, wqkvT + 2097152, 1024, 1024, dflag);
  transpose_kernel<<<dim3(32, 32), 256, 0, stream>>>(wo, woT,             1024, 1024, dflag);
  transpose_kernel<<<dim3(96, 32), 256, 0, stream>>>(w1, w1T,             1024, 3072, dflag);
  transpose_kernel<<<dim3(32, 96), 256, 0, stream>>>(w2, w2T,             3072, 1024, dflag);

  embed_kernel<<<TT, 256, 0, stream>>>(atoms, neighbors, atoms_emb, neigh_emb, xb, dflag);

  for (int layer = 0; layer < NLAYER; layer++) {
    // fused QKV: xb[8192][1024] @ wqkvT^T -> qkv [8192][3072]
    gemm_bt<1,3><<<dim3(24, 64), 256, 0, stream>>>(xb, wqkvT, bq, bk, bv, qkv,
                                                   1024, 3072, 1024, dflag);
    attn_kernel<<<BB * HH, 256, 0, stream>>>(qkv, distances, dist_emb, dflag);
    // WO: reads q-segment of qkv (lda=3072)
    gemm_bt<1,1><<<dim3(8, 64),  256, 0, stream>>>(qkv, woT, bo, bo, bo, tmp2,
                                                   3072, 1024, 1024, dflag);
    add_ln_kernel<<<TT, 256, 0, stream>>>(xb, tmp2, ln1_g, ln1_b, dflag);
    // FFN1 + GELU -> qkv region (dead)
    gemm_bt<2,1><<<dim3(24, 64), 256, 0, stream>>>(xb, w1T, b1, b1, b1, qkv,
                                                   1024, 3072, 1024, dflag);
    // FFN2
    gemm_bt<1,1><<<dim3(8, 64),  256, 0, stream>>>(qkv, w2T, b2, b2, b2, tmp2,
                                                   3072, 1024, 3072, dflag);
    add_ln_kernel<<<TT, 256, 0, stream>>>(xb, tmp2, ln2_g, ln2_b, dflag);
  }

  // move residual out of d_out, then rewrite d_out in the detected output dtype
  hipMemcpyAsync(tmp2, d_out, (size_t)TT * DD * 2, hipMemcpyDeviceToDevice, stream);
  finalize_kernel<<<TT, 256, 0, stream>>>(tmp2, d_out, dflag);
}

// Round 10
// 2502.819 us; speedup vs baseline: 1.6056x; 1.6056x over previous
//
#include <hip/hip_runtime.h>
#include <hip/hip_bf16.h>

#define BB 64
#define SS 128
#define DD 1024
#define HH 16
#define DHH 64
#define FF 3072
#define QS 3072      /* fused qkv row stride */
#define NLAYER 8
#define TT (BB*SS)   /* 8192 tokens */
#define NEGV -1e9f
#define EPSV 1e-5f

typedef __bf16 bf16;
typedef __bf16 bf16x4 __attribute__((ext_vector_type(4)));
typedef __bf16 bf16x8 __attribute__((ext_vector_type(8)));
typedef float f32x4 __attribute__((ext_vector_type(4)));

#define WS_NEEDED 88084480ull  /* 84 MB + flag page (proven available) */
#define FLAG_OFF  88080384ull

// dtype-flexible scalar load: f==1 -> fp32 data, f==0 -> bf16 data
__device__ __forceinline__ float ldf(const void* p, long idx, int f) {
  return f ? ((const float*)p)[idx] : (float)((const bf16*)p)[idx];
}

// diagnostic: report ws_size (in MB) through the output if workspace too small
__global__ __launch_bounds__(256) void diag_kernel(bf16* __restrict__ out, float val) {
  int base = blockIdx.x * 1024 + threadIdx.x * 4;
  for (int j = 0; j < 4; j++) out[base + j] = (bf16)val;
}

// ---------------- dtype detection: scan first 2048 halves of atoms_emb ----------------
__global__ __launch_bounds__(256) void detect_kernel(const unsigned short* __restrict__ p,
                                                     int n, int* __restrict__ flag) {
  __shared__ int sh[4];
  int found = 0;
  for (int i = threadIdx.x; i < n; i += 256) {
    unsigned e = (p[i] >> 7) & 0xFF;
    found |= (e >= 0x7F);
  }
  for (int d = 1; d < 64; d <<= 1) found |= __shfl_xor(found, d);
  if ((threadIdx.x & 63) == 0) sh[threadIdx.x >> 6] = found;
  __syncthreads();
  if (threadIdx.x == 0) *flag = sh[0] | sh[1] | sh[2] | sh[3];
}

// ---------------- weight transpose: W[K][N] (fp32 or bf16) -> WT[N][K] (bf16) ----------------
__global__ __launch_bounds__(256) void transpose_kernel(const void* __restrict__ W,
                                                        bf16* __restrict__ WT, int K, int N,
                                                        const int* __restrict__ dflag) {
  __shared__ bf16 tbuf[32][33];
  const int f = *dflag;
  int n0 = blockIdx.x * 32, k0 = blockIdx.y * 32;
  int tx = threadIdx.x & 31, ty = threadIdx.x >> 5;   // 32 x 8
  for (int i = 0; i < 4; i++)
    tbuf[ty + i*8][tx] = (bf16)ldf(W, (long)(k0 + ty + i*8) * N + n0 + tx, f);
  __syncthreads();
  for (int i = 0; i < 4; i++)
    WT[(long)(n0 + ty + i*8) * K + k0 + tx] = tbuf[tx][ty + i*8];
}

// ---------------- embedding ----------------
__global__ __launch_bounds__(256) void embed_kernel(const int* __restrict__ atoms,
                                                    const int* __restrict__ neigh,
                                                    const void* __restrict__ a_emb,
                                                    const void* __restrict__ n_emb,
                                                    bf16* __restrict__ xb,
                                                    const int* __restrict__ dflag) {
  const int f = *dflag;
  int t = blockIdx.x;
  int a = atoms[t], n = neigh[t];
  int c0 = threadIdx.x * 4;
  bf16x4 o;
  for (int j = 0; j < 4; j++) {
    float va = (a != 0) ? ldf(a_emb, (long)a * DD + c0 + j, f) : 0.0f;
    float vn = (n != 0) ? ldf(n_emb, (long)n * DD + c0 + j, f) : 0.0f;
    o[j] = (bf16)(va + vn);
  }
  *(bf16x4*)(xb + (long)t * DD + c0) = o;
}

// ---------------- GEMM: C[M][N] = A[M][K](lda) @ Bt[N][K]^T + bias ----------------
// EPI: 1 = bf16 out, 2 = + exact GELU, 3 = + residual add (resid[M][N], fp32 pre-round).
// NBIAS: 1 = bias[N], 3 = three 1024-biases.
// PROVEN-BEST structure (R7+R8 swizzle): 128x128 tile, BK=64 as two 32-k chunk buffers,
// both operands reg-staged through LDS, XOR-swizzled columns (measured 0 conflicts),
// next-tile global prefetch issued between the barriers so it overlaps the 32-MFMA phase.
template<int EPI, int NBIAS>
__global__ __launch_bounds__(256) void gemm_bt(const bf16* __restrict__ A,
                                               const bf16* __restrict__ Bt,
                                               const void* __restrict__ bp0,
                                               const void* __restrict__ bp1,
                                               const void* __restrict__ bp2,
                                               const bf16* __restrict__ resid,
                                               bf16* __restrict__ Cout,
                                               int lda, int N, int K,
                                               const int* __restrict__ dflag) {
  __shared__ __align__(16) bf16 Ald[2][128][32];
  __shared__ __align__(16) bf16 Bld[2][128][32];
  const int f = *dflag;
  const int tid  = threadIdx.x;
  const int l    = tid & 63;
  const int quad = l >> 4, l16 = l & 15;
  const int w    = tid >> 6, wr = w >> 1, wc = w & 1;
  const int m0   = blockIdx.y * 128;
  const int n0   = blockIdx.x * 128;

  // staging: row r0 / r0+64, 16B chunk c0; swizzled LDS column (bits1-2 of row)
  const int r0 = tid >> 2, c0 = tid & 3;
  const int cs = (c0 ^ ((r0 >> 1) & 3)) * 8;      // store column
  const int cr = (quad ^ ((l16 >> 1) & 3)) * 8;   // read column (same swizzle)
  const bf16* Ap0 = A  + (long)(m0 + r0)      * lda + c0*8;
  const bf16* Ap1 = A  + (long)(m0 + 64 + r0) * lda + c0*8;
  const bf16* Bp0 = Bt + (long)(n0 + r0)      * K   + c0*8;
  const bf16* Bp1 = Bt + (long)(n0 + 64 + r0) * K   + c0*8;

  f32x4 acc[4][4] = {};

  bf16x8 ra[2][2], rb[2][2];   // [chunk][row-half]
  for (int s = 0; s < 2; s++) {
    ra[s][0] = *(const bf16x8*)(Ap0 + s*32);
    ra[s][1] = *(const bf16x8*)(Ap1 + s*32);
    rb[s][0] = *(const bf16x8*)(Bp0 + s*32);
    rb[s][1] = *(const bf16x8*)(Bp1 + s*32);
  }

  for (int kt = 0; kt < K; kt += 64) {
    for (int s = 0; s < 2; s++) {
      *(bf16x8*)&Ald[s][r0][cs]      = ra[s][0];
      *(bf16x8*)&Ald[s][64 + r0][cs] = ra[s][1];
      *(bf16x8*)&Bld[s][r0][cs]      = rb[s][0];
      *(bf16x8*)&Bld[s][64 + r0][cs] = rb[s][1];
    }
    __syncthreads();   // tiles visible

    if (kt + 64 < K) {       // prefetch next K-tile (overlaps the 32-MFMA phase)
      const int kn = kt + 64;
      for (int s = 0; s < 2; s++) {
        ra[s][0] = *(const bf16x8*)(Ap0 + kn + s*32);
        ra[s][1] = *(const bf16x8*)(Ap1 + kn + s*32);
        rb[s][0] = *(const bf16x8*)(Bp0 + kn + s*32);
        rb[s][1] = *(const bf16x8*)(Bp1 + kn + s*32);
      }
    }

    for (int s = 0; s < 2; s++) {
      bf16x8 af[4], bfr[4];
      for (int i = 0; i < 4; i++)
        af[i] = *(const bf16x8*)&Ald[s][wr*64 + i*16 + l16][cr];
      for (int j = 0; j < 4; j++)
        bfr[j] = *(const bf16x8*)&Bld[s][wc*64 + j*16 + l16][cr];
      for (int i = 0; i < 4; i++)
        for (int j = 0; j < 4; j++)
          acc[i][j] = __builtin_amdgcn_mfma_f32_16x16x32_bf16(af[i], bfr[j], acc[i][j], 0, 0, 0);
    }
    __syncthreads();   // readers done before next stores
  }

  for (int i = 0; i < 4; i++) {
    for (int j = 0; j < 4; j++) {
      int col = n0 + wc*64 + j*16 + l16;
      float bv;
      if (NBIAS == 3) {
        int seg = col >> 10, off = col & 1023;
        const void* bp = (seg == 0) ? bp0 : ((seg == 1) ? bp1 : bp2);
        bv = ldf(bp, off, f);
      } else {
        bv = ldf(bp0, col, f);
      }
      for (int r = 0; r < 4; r++) {
        int row = m0 + wr*64 + i*16 + quad*4 + r;
        float v = acc[i][j][r] + bv;
        if (EPI == 2) v = 0.5f * v * (1.0f + erff(v * 0.70710678118f));
        if (EPI == 3) v += (float)resid[(long)row * N + col];
        Cout[(long)row * N + col] = (bf16)v;
      }
    }
  }
}

// ---------------- attention on fused qkv buffer: one block per (b,h) ----------------
__global__ __launch_bounds__(256) void attn_kernel(bf16* __restrict__ qkv,
                                                   const int* __restrict__ dist,
                                                   const void* __restrict__ demb,
                                                   const int* __restrict__ dflag) {
  __shared__ __align__(16) bf16 Vt[DHH][SS + 8];
  __shared__ __align__(16) bf16 Pb[4][32][SS + 8];
  __shared__ float dtab[16];
  const int f = *dflag;
  const int b = blockIdx.x >> 4, h = blockIdx.x & 15;
  const int tid = threadIdx.x;
  const int w = tid >> 6, l = tid & 63, quad = l >> 4, l16 = l & 15;
  if (tid < 13) dtab[tid] = (tid == 0) ? NEGV : ldf(demb, tid * HH + h, f);

  const long rowb = (long)b * SS;
  for (int i = 0; i < 4; i++) {
    int task = tid + i * 256;
    int kk = task >> 3, ng = task & 7;
    bf16x8 vv = *(const bf16x8*)(qkv + (rowb + kk) * QS + 2048 + h*DHH + ng*8);
    for (int u = 0; u < 8; u++) Vt[ng*8 + u][kk] = vv[u];
  }
  __syncthreads();

  const int qbase = w * 32;
  f32x4 acc[2][8] = {};
  for (int ks = 0; ks < 2; ks++) {
    bf16x8 af[2];
    for (int ti = 0; ti < 2; ti++)
      af[ti] = *(const bf16x8*)(qkv + (rowb + qbase + ti*16 + l16) * QS + h*DHH + ks*32 + quad*8);
    for (int tj = 0; tj < 8; tj++) {
      bf16x8 bfr = *(const bf16x8*)(qkv + (rowb + tj*16 + l16) * QS + 1024 + h*DHH + ks*32 + quad*8);
      for (int ti = 0; ti < 2; ti++)
        acc[ti][tj] = __builtin_amdgcn_mfma_f32_16x16x32_bf16(af[ti], bfr, acc[ti][tj], 0, 0, 0);
    }
  }

  const float scale = 0.125f;  // 1/sqrt(64)
  for (int ti = 0; ti < 2; ti++) {
    for (int r = 0; r < 4; r++) {
      int q = qbase + ti*16 + quad*4 + r;
      const int* drow = dist + (rowb + q) * SS;
      float vals[8];
      float mx = -3.0e38f;
      for (int tj = 0; tj < 8; tj++) {
        float sv = acc[ti][tj][r] * scale + dtab[drow[tj*16 + l16]];
        vals[tj] = sv; mx = fmaxf(mx, sv);
      }
      for (int d2 = 1; d2 < 16; d2 <<= 1) mx = fmaxf(mx, __shfl_xor(mx, d2));
      float sm = 0.0f;
      for (int tj = 0; tj < 8; tj++) { vals[tj] = __expf(vals[tj] - mx); sm += vals[tj]; }
      for (int d2 = 1; d2 < 16; d2 <<= 1) sm += __shfl_xor(sm, d2);
      float inv = 1.0f / sm;
      int pr = ti*16 + quad*4 + r;
      for (int tj = 0; tj < 8; tj++)
        Pb[w][pr][tj*16 + l16] = (bf16)(vals[tj] * inv);
    }
  }
  __syncthreads();

  f32x4 acc2[2][4] = {};
  for (int ks = 0; ks < 4; ks++) {
    bf16x8 af[2];
    for (int ti = 0; ti < 2; ti++)
      af[ti] = *(const bf16x8*)&Pb[w][ti*16 + l16][ks*32 + quad*8];
    for (int tj = 0; tj < 4; tj++) {
      bf16x8 bfr = *(const bf16x8*)&Vt[tj*16 + l16][ks*32 + quad*8];
      for (int ti = 0; ti < 2; ti++)
        acc2[ti][tj] = __builtin_amdgcn_mfma_f32_16x16x32_bf16(af[ti], bfr, acc2[ti][tj], 0, 0, 0);
    }
  }
  for (int ti = 0; ti < 2; ti++)
    for (int tj = 0; tj < 4; tj++)
      for (int r = 0; r < 4; r++) {
        int q = qbase + ti*16 + quad*4 + r;
        qkv[(rowb + q) * QS + h*DHH + tj*16 + l16] = (bf16)acc2[ti][tj][r];
      }
}

// ---------------- LayerNorm: reads pre-summed (resid+sublayer) row, writes xb ----------------
__global__ __launch_bounds__(256) void ln_kernel(const bf16* __restrict__ sum,
                                                 bf16* __restrict__ xb,
                                                 const void* __restrict__ g,
                                                 const void* __restrict__ bta,
                                                 const int* __restrict__ dflag) {
  const int f = *dflag;
  int r = blockIdx.x, tid = threadIdx.x;
  int c0 = tid * 4;
  bf16x4 sv = *(const bf16x4*)(sum + (long)r*DD + c0);
  float v[4];
  for (int j = 0; j < 4; j++) v[j] = (float)sv[j];
  float s  = v[0] + v[1] + v[2] + v[3];
  float s2 = v[0]*v[0] + v[1]*v[1] + v[2]*v[2] + v[3]*v[3];
  for (int d2 = 1; d2 < 64; d2 <<= 1) { s += __shfl_xor(s, d2); s2 += __shfl_xor(s2, d2); }
  __shared__ float ws1[4], ws2[4];
  int w = tid >> 6, l = tid & 63;
  if (l == 0) { ws1[w] = s; ws2[w] = s2; }
  __syncthreads();
  s  = ws1[0] + ws1[1] + ws1[2] + ws1[3];
  s2 = ws2[0] + ws2[1] + ws2[2] + ws2[3];
  float mu  = s * (1.0f / DD);
  float var = s2 * (1.0f / DD) - mu * mu;
  float rs  = rsqrtf(var + EPSV);
  bf16x4 o;
  for (int j = 0; j < 4; j++)
    o[j] = (bf16)((v[j] - mu) * rs * ldf(g, c0 + j, f) + ldf(bta, c0 + j, f));
  *(bf16x4*)(xb + (long)r*DD + c0) = o;
}

// ---------------- finalize: bf16 scratch -> d_out in detected dtype; NaN tripwire ----------------
__global__ __launch_bounds__(256) void finalize_kernel(const bf16* __restrict__ src,
                                                       void* __restrict__ dst,
                                                       const int* __restrict__ dflag) {
  const int f = *dflag;
  long i = (long)blockIdx.x * 1024 + threadIdx.x * 4;
  for (int j = 0; j < 4; j++) {
    float v = (float)src[i + j];
    if (v != v) v = 777.0f;
    if (f) ((float*)dst)[i + j] = v;
    else   ((bf16*)dst)[i + j] = (bf16)v;
  }
}

extern "C" void kernel_launch(void* const* d_in, const int* in_sizes, int n_in,
                              void* d_out, int out_size, void* d_ws, size_t ws_size,
                              hipStream_t stream) {
  (void)in_sizes; (void)n_in; (void)out_size;
  const int*  atoms     = (const int*)d_in[0];
  const int*  neighbors = (const int*)d_in[1];
  const int*  distances = (const int*)d_in[2];
  const void* atoms_emb = d_in[3];
  const void* neigh_emb = d_in[4];
  const void* dist_emb  = d_in[5];
  const void* wq = d_in[6];
  const void* bq = d_in[7];
  const void* wk = d_in[8];
  const void* bk = d_in[9];
  const void* wv = d_in[10];
  const void* bv = d_in[11];
  const void* wo = d_in[12];
  const void* bo = d_in[13];
  const void* ln1_g = d_in[14];
  const void* ln1_b = d_in[15];
  const void* w1 = d_in[16];
  const void* b1 = d_in[17];
  const void* w2 = d_in[18];
  const void* b2 = d_in[19];
  const void* ln2_g = d_in[20];
  const void* ln2_b = d_in[21];

  if (ws_size < WS_NEEDED) {
    diag_kernel<<<TT, 256, 0, stream>>>((bf16*)d_out, (float)(ws_size >> 20));
    return;
  }

  char* ws = (char*)d_ws;
  bf16* qkv   = (bf16*)(ws);                  // [8192][3072] fused q|k|v; also FFN hbuf
  bf16* tmp2  = (bf16*)(ws + 50331648);       // [8192][1024] residual+sublayer sum
  bf16* wqkvT = (bf16*)(ws + 67108864);       // [3072][1024]
  bf16* woT   = (bf16*)(ws + 73400320);       // [1024][1024]
  bf16* w1T   = (bf16*)(ws + 75497472);       // [3072][1024]
  bf16* w2T   = (bf16*)(ws + 81788928);       // [1024][3072]
  int*  dflag = (int*)(ws + FLAG_OFF);
  bf16* xb    = (bf16*)d_out;                 // bf16 residual stream

  detect_kernel<<<1, 256, 0, stream>>>((const unsigned short*)atoms_emb, 2048, dflag);

  transpose_kernel<<<dim3(32, 32), 256, 0, stream>>>(wq, wqkvT,           1024, 1024, dflag);
  transpose_kernel<<<dim3(32, 32), 256, 0, stream>>>(wk, wqkvT + 1048576, 1024, 1024, dflag);
  transpose_kernel<<<dim3(32, 32), 256, 0, stream>>>(wv, wqkvT + 2097152, 1024, 1024, dflag);
  transpose_kernel<<<dim3(32, 32), 256, 0, stream>>>(wo, woT,             1024, 1024, dflag);
  transpose_kernel<<<dim3(96, 32), 256, 0, stream>>>(w1, w1T,             1024, 3072, dflag);
  transpose_kernel<<<dim3(32, 96), 256, 0, stream>>>(w2, w2T,             3072, 1024, dflag);

  embed_kernel<<<TT, 256, 0, stream>>>(atoms, neighbors, atoms_emb, neigh_emb, xb, dflag);

  for (int layer = 0; layer < NLAYER; layer++) {
    // fused QKV: xb[8192][1024] @ wqkvT^T -> qkv [8192][3072]
    gemm_bt<1,3><<<dim3(24, 64), 256, 0, stream>>>(xb, wqkvT, bq, bk, bv, nullptr,
                                                   qkv, 1024, 3072, 1024, dflag);
    attn_kernel<<<BB * HH, 256, 0, stream>>>(qkv, distances, dist_emb, dflag);
    // WO (+bias +residual xb): reads q-segment of qkv (lda=3072) -> tmp2 = x + sublayer
    gemm_bt<3,1><<<dim3(8, 64),  256, 0, stream>>>(qkv, woT, bo, bo, bo, xb,
                                                   tmp2, 3072, 1024, 1024, dflag);
    ln_kernel<<<TT, 256, 0, stream>>>(tmp2, xb, ln1_g, ln1_b, dflag);
    // FFN1 + GELU -> qkv region (dead)
    gemm_bt<2,1><<<dim3(24, 64), 256, 0, stream>>>(xb, w1T, b1, b1, b1, nullptr,
                                                   qkv, 1024, 3072, 1024, dflag);
    // FFN2 (+bias +residual xb) -> tmp2
    gemm_bt<3,1><<<dim3(8, 64),  256, 0, stream>>>(qkv, w2T, b2, b2, b2, xb,
                                                   tmp2, 3072, 1024, 3072, dflag);
    ln_kernel<<<TT, 256, 0, stream>>>(tmp2, xb, ln2_g, ln2_b, dflag);
  }

  // move residual out of d_out, then rewrite d_out in the detected output dtype
  hipMemcpyAsync(tmp2, d_out, (size_t)TT * DD * 2, hipMemcpyDeviceToDevice, stream);
  finalize_kernel<<<TT, 256, 0, stream>>>(tmp2, d_out, dflag);
}